// Round 7
// baseline (343.546 us; speedup 1.0000x reference)
//
#include <hip/hip_runtime.h>

// obj = (99*sum_t ||c_t||^2 + ||sum_t c_t||^2)/100 (Parseval over the 100
// samples = 99th roots of unity, z=1 double-counted), c_0 = D_F,
// c_{k+1} = E_k = C_F A_F^k B_F - C A^k B, B = eye(256,128), k=0..7.
//
// POWER-DOUBLING dataflow (verified, absmax 0.0 in rounds 5/6):
//   P1: AF2(+b)=AF*AF, G1=CF*AF, A2(+b)=A*A, H1=C*A (+copies G0,H0,Sm,BFb)
//   P2: AF4b=bf16(AF2f*AF2b), [G2;G3]=G[0:256]*AF2b, A4b, [H2;H3]
//   P3: [G4..G7]=G[0:512]*AF4b, [H4..H7]=H[0:512]*A4b
//   P4: E=G*BFb - H[:,:128]; S1+=|E|^2; Sm+=E; ticketed finalize.
// Round-6 post-mortem: inner loop was LDS-THROUGHPUT-bound (per kk: b128+b32
// for 8 FMA ~= 18 cyc LDS vs 16 cyc VALU on a per-CU-shared LDS pipe ->
// VALUBusy 16% regardless of occupancy) + 147K bank conflicts from kk-major
// Q staging. This revision: thread tile 2 rows x 4 cols (acc[16]) -> per 2kk:
// 4x b128 (48 cyc LDS) vs 64 FMA + unpack (~160 cyc VALU), 1:3 ratio; block
// tile 16x128, K-chunk 64 (LDS 40 KB); Q staged ROW-major [row][kk] (bank-
// spread writes, 2-addr broadcast reads). Same bf16 points -> same numerics.

struct Params {
    const float *AFr, *AFi, *Ar, *Ai, *BFr, *BFi, *CFr, *CFi, *Cr, *Ci, *DFr, *DFi;
    float2 *Gf, *Hf, *AF2f, *A2f, *Sm;          // fp32 complex buffers
    unsigned int *AF2b, *AF4b, *A2b, *A4b, *BFb; // packed bf16 tables
    float *S1; unsigned int *tick; float *out;
};

__device__ __forceinline__ unsigned int pk_bf16(float r, float i) {
    unsigned int u;
    asm("v_cvt_pk_bf16_f32 %0, %1, %2" : "=v"(u) : "v"(r), "v"(i));
    return u;   // low16 = bf16(r), high16 = bf16(i)
}

// system-scope (LLC) 8B load — used only for the final Sm read after atomics
__device__ __forceinline__ float2 ld_sys(const float2* p) {
    unsigned long long v = __hip_atomic_load((const unsigned long long*)p,
                                 __ATOMIC_RELAXED, __HIP_MEMORY_SCOPE_SYSTEM);
    union { unsigned long long u; float2 f; } c; c.u = v; return c.f;
}

__device__ __forceinline__ float block_reduce(float v, float* red, int tid) {
    red[tid] = v;
    __syncthreads();
    for (int off = 128; off > 0; off >>= 1) {
        if (tid < off) red[tid] += red[tid + off];
        __syncthreads();
    }
    float r = red[0];
    __syncthreads();
    return r;
}

// one complex MAC against a packed-bf16 word (compiler CSEs the unpacks)
#define CM(wd, ar, ai, o)                                              \
    { float br_ = __uint_as_float((wd) << 16);                         \
      float bi_ = __uint_as_float((wd) & 0xffff0000u);                 \
      acc[o]     += (ar) * br_ - (ai) * bi_;                           \
      acc[(o)+1] += (ar) * bi_ + (ai) * br_; }

// ---- GEMM: block tile 16 rows x 128 cols at (rg*16 [+Rbase], c0).
// K = NCH*64, chunked through LDS. Thread (w=tid>>6, hi=(tid>>5)&1, cc=tid&31)
// owns rows {4w+2hi, +1}, cols {c0+4cc .. +3}: acc[16] (8 complexes).
// Q fp32 (split r/i arrays or float2 buffer), B packed bf16 (on-the-fly
// converted from fp32 pair, or copied from a table).
template<int NCH, bool QSPLIT, bool BCONV>
__device__ __forceinline__ void gemm16(
    const float* __restrict__ Qr_, const float* __restrict__ Qi_,
    const float2* __restrict__ Qf, int Wq,
    const float* __restrict__ Br_, const float* __restrict__ Bi_,
    const unsigned int* __restrict__ Bb, int Wb,
    int c0, int rg, unsigned int* sBu, float2* sQ, float* acc) {
    const int tid = threadIdx.x;
    const int w = tid >> 6, hi = (tid >> 5) & 1, cc = tid & 31;
    const int r0 = 4 * w + 2 * hi;
    #pragma unroll 1
    for (int ch = 0; ch < NCH; ++ch) {
        if (ch) __syncthreads();             // prior chunk's readers done
        const int kk0 = ch * 64;
        // B slab: 64 rows x 128 u32 = 2048 uint4 slots
        #pragma unroll
        for (int j = 0; j < 8; ++j) {
            int slot = tid + j * 256;
            int row = slot >> 5, cq = (slot & 31) << 2;
            int g = (kk0 + row) * Wb + c0 + cq;
            if constexpr (BCONV) {
                float4 vr = *(const float4*)&Br_[g];
                float4 vi = *(const float4*)&Bi_[g];
                *(uint4*)&sBu[(row << 7) + cq] = make_uint4(
                    pk_bf16(vr.x, vi.x), pk_bf16(vr.y, vi.y),
                    pk_bf16(vr.z, vi.z), pk_bf16(vr.w, vi.w));
            } else {
                *(uint4*)&sBu[(row << 7) + cq] = *(const uint4*)&Bb[g];
            }
        }
        // Q: 16 rows x 64 kk f2, ROW-major [row][kk] (512 float4 slots)
        #pragma unroll
        for (int j = 0; j < 2; ++j) {
            int slot = tid + j * 256;
            int row = slot >> 5, k2 = (slot & 31) << 1;
            int gq = (rg * 16 + row) * Wq + kk0 + k2;
            float4 v;
            if constexpr (QSPLIT) {
                float2 r2 = *(const float2*)&Qr_[gq];
                float2 i2 = *(const float2*)&Qi_[gq];
                v = make_float4(r2.x, i2.x, r2.y, i2.y);
            } else {
                v = *(const float4*)&Qf[gq];
            }
            *(float4*)&sQ[(row << 6) + k2] = v;
        }
        __syncthreads();
        #pragma unroll 4
        for (int kk = 0; kk < 64; kk += 2) {
            float4 qa = *(const float4*)&sQ[(r0 << 6) + kk];        // row r0:   kk,kk+1
            float4 qb = *(const float4*)&sQ[((r0 + 1) << 6) + kk];  // row r0+1: kk,kk+1
            uint4 b0 = *(const uint4*)&sBu[(kk << 7) + (cc << 2)];
            uint4 b1 = *(const uint4*)&sBu[((kk + 1) << 7) + (cc << 2)];
            CM(b0.x, qa.x, qa.y, 0)  CM(b0.y, qa.x, qa.y, 2)
            CM(b0.z, qa.x, qa.y, 4)  CM(b0.w, qa.x, qa.y, 6)
            CM(b0.x, qb.x, qb.y, 8)  CM(b0.y, qb.x, qb.y, 10)
            CM(b0.z, qb.x, qb.y, 12) CM(b0.w, qb.x, qb.y, 14)
            CM(b1.x, qa.z, qa.w, 0)  CM(b1.y, qa.z, qa.w, 2)
            CM(b1.z, qa.z, qa.w, 4)  CM(b1.w, qa.z, qa.w, 6)
            CM(b1.x, qb.z, qb.w, 8)  CM(b1.y, qb.z, qb.w, 10)
            CM(b1.z, qb.z, qb.w, 12) CM(b1.w, qb.z, qb.w, 14)
        }
    }
}

// epilogues: one row of 4 consecutive cols from acc8 (cols c0+4cc..+3)
__device__ __forceinline__ void st_f(float2* O, int W, int prow, int col0,
                                     const float* a8) {
    *(float4*)&O[prow * W + col0]     = make_float4(a8[0], a8[1], a8[2], a8[3]);
    *(float4*)&O[prow * W + col0 + 2] = make_float4(a8[4], a8[5], a8[6], a8[7]);
}
__device__ __forceinline__ void st_b(unsigned int* O, int W, int prow, int col0,
                                     const float* a8) {
    *(uint4*)&O[prow * W + col0] = make_uint4(
        pk_bf16(a8[0], a8[1]), pk_bf16(a8[2], a8[3]),
        pk_bf16(a8[4], a8[5]), pk_bf16(a8[6], a8[7]));
}

// ---------------- P1: AF2(+b), G1, A2(+b), H1, copies (160 blocks) ----------
// [0,72): AF2 24rg x 3cs  [72,96): G1 8x3  [96,128): A2 16x2  [128,144): H1 8x2
// [144,160): copies G0=CF, H0=C, Sm=DF, BFb=pk(BF)
__global__ __launch_bounds__(256, 2)
void p1_kernel(Params P) {
    __shared__ __align__(16) unsigned int sBu[64 * 128];  // 32 KB
    __shared__ __align__(16) float2 sQ[16 * 64];          // 8 KB
    const int b = blockIdx.x, tid = threadIdx.x;
    const int w = tid >> 6, hi = (tid >> 5) & 1, cc = tid & 31;
    const int r0 = 4 * w + 2 * hi, col0 = cc << 2;
    float acc[16] = {};
    if (b < 72) {
        int rg = b / 3, cs = b - 3 * rg;
        gemm16<6, true, true>(P.AFr, P.AFi, nullptr, 384, P.AFr, P.AFi, nullptr, 384,
                              cs << 7, rg, sBu, sQ, acc);
        const int prow = rg * 16 + r0, pc = (cs << 7) + col0;
        st_f(P.AF2f, 384, prow, pc, acc);     st_f(P.AF2f, 384, prow + 1, pc, acc + 8);
        st_b(P.AF2b, 384, prow, pc, acc);     st_b(P.AF2b, 384, prow + 1, pc, acc + 8);
    } else if (b < 96) {
        int u = b - 72, rg = u / 3, cs = u - 3 * rg;
        gemm16<6, true, true>(P.CFr, P.CFi, nullptr, 384, P.AFr, P.AFi, nullptr, 384,
                              cs << 7, rg, sBu, sQ, acc);
        float2* O = P.Gf + 128 * 384;                           // G1 rows 128..255
        const int prow = rg * 16 + r0, pc = (cs << 7) + col0;
        st_f(O, 384, prow, pc, acc);          st_f(O, 384, prow + 1, pc, acc + 8);
    } else if (b < 128) {
        int u = b - 96, rg = u >> 1, cs = u & 1;
        gemm16<4, true, true>(P.Ar, P.Ai, nullptr, 256, P.Ar, P.Ai, nullptr, 256,
                              cs << 7, rg, sBu, sQ, acc);
        const int prow = rg * 16 + r0, pc = (cs << 7) + col0;
        st_f(P.A2f, 256, prow, pc, acc);      st_f(P.A2f, 256, prow + 1, pc, acc + 8);
        st_b(P.A2b, 256, prow, pc, acc);      st_b(P.A2b, 256, prow + 1, pc, acc + 8);
    } else if (b < 144) {
        int u = b - 128, rg = u >> 1, cs = u & 1;
        gemm16<4, true, true>(P.Cr, P.Ci, nullptr, 256, P.Ar, P.Ai, nullptr, 256,
                              cs << 7, rg, sBu, sQ, acc);
        float2* O = P.Hf + 128 * 256;                           // H1 rows 128..255
        const int prow = rg * 16 + r0, pc = (cs << 7) + col0;
        st_f(O, 256, prow, pc, acc);          st_f(O, 256, prow + 1, pc, acc + 8);
    } else {
        for (int i = (b - 144) * 256 + tid; i < 147456; i += 16 * 256) {
            if (i < 49152)        P.Gf[i] = make_float2(P.CFr[i], P.CFi[i]);          // G0
            else if (i < 81920)  { int j = i - 49152; P.Hf[j] = make_float2(P.Cr[j], P.Ci[j]); }  // H0
            else if (i < 98304)  { int j = i - 81920; P.Sm[j] = make_float2(P.DFr[j], P.DFi[j]); }
            else                 { int j = i - 98304; P.BFb[j] = pk_bf16(P.BFr[j], P.BFi[j]); }
        }
    }
}

// ---------------- P2: AF4b, [G2;G3], A4b, [H2;H3] (184 blocks) --------------
// [0,72): AF4b 24x3  [72,120): G23 16x3  [120,152): A4b 16x2  [152,184): H23 16x2
__global__ __launch_bounds__(256, 2)
void p2_kernel(Params P) {
    __shared__ __align__(16) unsigned int sBu[64 * 128];
    __shared__ __align__(16) float2 sQ[16 * 64];
    const int b = blockIdx.x, tid = threadIdx.x;
    const int w = tid >> 6, hi = (tid >> 5) & 1, cc = tid & 31;
    const int r0 = 4 * w + 2 * hi, col0 = cc << 2;
    float acc[16] = {};
    if (b < 72) {
        int rg = b / 3, cs = b - 3 * rg;
        gemm16<6, false, false>(nullptr, nullptr, P.AF2f, 384, nullptr, nullptr, P.AF2b, 384,
                                cs << 7, rg, sBu, sQ, acc);
        const int prow = rg * 16 + r0, pc = (cs << 7) + col0;
        st_b(P.AF4b, 384, prow, pc, acc);     st_b(P.AF4b, 384, prow + 1, pc, acc + 8);
    } else if (b < 120) {
        int u = b - 72, rg = u / 3, cs = u - 3 * rg;            // rg 0..15 (G0,G1 rows)
        gemm16<6, false, false>(nullptr, nullptr, P.Gf, 384, nullptr, nullptr, P.AF2b, 384,
                                cs << 7, rg, sBu, sQ, acc);
        float2* O = P.Gf + 256 * 384;                           // G2,G3 rows 256..511
        const int prow = rg * 16 + r0, pc = (cs << 7) + col0;
        st_f(O, 384, prow, pc, acc);          st_f(O, 384, prow + 1, pc, acc + 8);
    } else if (b < 152) {
        int u = b - 120, rg = u >> 1, cs = u & 1;
        gemm16<4, false, false>(nullptr, nullptr, P.A2f, 256, nullptr, nullptr, P.A2b, 256,
                                cs << 7, rg, sBu, sQ, acc);
        const int prow = rg * 16 + r0, pc = (cs << 7) + col0;
        st_b(P.A4b, 256, prow, pc, acc);      st_b(P.A4b, 256, prow + 1, pc, acc + 8);
    } else {
        int u = b - 152, rg = u >> 1, cs = u & 1;               // rg 0..15 (H0,H1 rows)
        gemm16<4, false, false>(nullptr, nullptr, P.Hf, 256, nullptr, nullptr, P.A2b, 256,
                                cs << 7, rg, sBu, sQ, acc);
        float2* O = P.Hf + 256 * 256;                           // H2,H3 rows 256..511
        const int prow = rg * 16 + r0, pc = (cs << 7) + col0;
        st_f(O, 256, prow, pc, acc);          st_f(O, 256, prow + 1, pc, acc + 8);
    }
}

// ---------------- P3: [G4..G7], [H4..H7] (160 blocks) -----------------------
// [0,96): G4567 32x3    [96,160): H4567 32x2
__global__ __launch_bounds__(256, 2)
void p3_kernel(Params P) {
    __shared__ __align__(16) unsigned int sBu[64 * 128];
    __shared__ __align__(16) float2 sQ[16 * 64];
    const int b = blockIdx.x, tid = threadIdx.x;
    const int w = tid >> 6, hi = (tid >> 5) & 1, cc = tid & 31;
    const int r0 = 4 * w + 2 * hi, col0 = cc << 2;
    float acc[16] = {};
    if (b < 96) {
        int rg = b / 3, cs = b - 3 * rg;                        // rg 0..31 (G0..G3 rows)
        gemm16<6, false, false>(nullptr, nullptr, P.Gf, 384, nullptr, nullptr, P.AF4b, 384,
                                cs << 7, rg, sBu, sQ, acc);
        float2* O = P.Gf + 512 * 384;                           // G4..7 rows 512..1023
        const int prow = rg * 16 + r0, pc = (cs << 7) + col0;
        st_f(O, 384, prow, pc, acc);          st_f(O, 384, prow + 1, pc, acc + 8);
    } else {
        int u = b - 96, rg = u >> 1, cs = u & 1;                // rg 0..31 (H0..H3 rows)
        gemm16<4, false, false>(nullptr, nullptr, P.Hf, 256, nullptr, nullptr, P.A4b, 256,
                                cs << 7, rg, sBu, sQ, acc);
        float2* O = P.Hf + 512 * 256;                           // H4..7 rows 512..1023
        const int prow = rg * 16 + r0, pc = (cs << 7) + col0;
        st_f(O, 256, prow, pc, acc);          st_f(O, 256, prow + 1, pc, acc + 8);
    }
}

// ---------------- P4: E + reductions + ticketed finalize (64 blocks) --------
// rg = b: E rows rg*16..+15 of the 1024-row stack, all 128 cols.
__global__ __launch_bounds__(256, 2)
void p4_kernel(Params P) {
    __shared__ __align__(16) unsigned int sBu[64 * 128];
    __shared__ __align__(16) float2 sQ[16 * 64];
    __shared__ float red[256];
    __shared__ int lastf;
    const int b = blockIdx.x, tid = threadIdx.x;
    const int w = tid >> 6, hi = (tid >> 5) & 1, cc = tid & 31;
    const int r0 = 4 * w + 2 * hi, col0 = cc << 2;
    float acc[16] = {};
    gemm16<6, false, false>(nullptr, nullptr, P.Gf, 384, nullptr, nullptr, P.BFb, 128,
                            0, b, sBu, sQ, acc);
    const int prow = b * 16 + r0;
    float* SmF = (float*)P.Sm;
    float t1 = 0.f;
    #pragma unroll
    for (int r = 0; r < 2; ++r) {
        const float* a8 = acc + 8 * r;
        const int pr = prow + r;
        float4 h0 = *(const float4*)&P.Hf[pr * 256 + col0];
        float4 h1 = *(const float4*)&P.Hf[pr * 256 + col0 + 2];
        float e[8];
        e[0] = a8[0] - h0.x; e[1] = a8[1] - h0.y; e[2] = a8[2] - h0.z; e[3] = a8[3] - h0.w;
        e[4] = a8[4] - h1.x; e[5] = a8[5] - h1.y; e[6] = a8[6] - h1.z; e[7] = a8[7] - h1.w;
        #pragma unroll
        for (int j = 0; j < 8; ++j) t1 += e[j] * e[j];
        int base = ((pr & 127) * 128 + col0) * 2;
        #pragma unroll
        for (int j = 0; j < 8; ++j) atomicAdd(&SmF[base + j], e[j]);
    }
    t1 = block_reduce(t1, red, tid);
    if (tid == 0) atomicAdd(P.S1, t1);
    __syncthreads();   // all this block's atomics drained before ticket
    if (tid == 0) lastf = (atomicAdd(P.tick, 1u) == 63u) ? 1 : 0;
    __syncthreads();
    if (lastf) {       // all other blocks' atomics are at the coherence point
        float s2 = 0.f, sd = 0.f;
        for (int i = tid; i < 16384; i += 256) {
            float2 sm = ld_sys(&P.Sm[i]);
            s2 += sm.x * sm.x + sm.y * sm.y;
            float dr = P.DFr[i], di = P.DFi[i];
            sd += dr * dr + di * di;
        }
        s2 = block_reduce(s2, red, tid);
        sd = block_reduce(sd, red, tid);
        if (tid == 0) {
            float s1 = atomicAdd(P.S1, 0.f);
            P.out[0] = (99.0f * (s1 + sd) + s2) / 100.0f;
        }
    }
}

extern "C" void kernel_launch(void* const* d_in, const int* in_sizes, int n_in,
                              void* d_out, int out_size, void* d_ws, size_t ws_size,
                              hipStream_t stream) {
    (void)in_sizes; (void)n_in; (void)out_size; (void)ws_size;
    char* ws = (char*)d_ws;
    Params h;
    h.Cr  = (const float*)d_in[0];
    h.Ci  = (const float*)d_in[1];
    h.Ar  = (const float*)d_in[2];
    h.Ai  = (const float*)d_in[3];
    h.AFr = (const float*)d_in[4];
    h.AFi = (const float*)d_in[5];
    h.BFr = (const float*)d_in[6];
    h.BFi = (const float*)d_in[7];
    h.CFr = (const float*)d_in[8];
    h.CFi = (const float*)d_in[9];
    h.DFr = (const float*)d_in[10];
    h.DFi = (const float*)d_in[11];
    h.Gf   = (float2*)(ws + 0);                  // 1024x384 c64 = 3145728 B
    h.Hf   = (float2*)(ws + 3145728);            // 1024x256 c64 = 2097152 B
    h.AF2f = (float2*)(ws + 5242880);            // 384x384 c64  = 1179648 B
    h.A2f  = (float2*)(ws + 6422528);            // 256x256 c64  =  524288 B
    h.AF2b = (unsigned int*)(ws + 6946816);      // 384x384 u32  =  589824 B
    h.AF4b = (unsigned int*)(ws + 7536640);      //               589824 B
    h.A2b  = (unsigned int*)(ws + 8126464);      // 256x256 u32  =  262144 B
    h.A4b  = (unsigned int*)(ws + 8388608);      //               262144 B
    h.BFb  = (unsigned int*)(ws + 8650752);      // 384x128 u32  =  196608 B
    h.Sm   = (float2*)(ws + 8847360);            // 128x128 c64  =  131072 B
    h.S1   = (float*)(ws + 8978432);
    h.tick = (unsigned int*)(ws + 8978436);
    h.out  = (float*)d_out;

    hipMemsetAsync(ws + 8978432, 0, 8, stream);  // S1, tick
    p1_kernel<<<160, 256, 0, stream>>>(h);
    p2_kernel<<<184, 256, 0, stream>>>(h);
    p3_kernel<<<160, 256, 0, stream>>>(h);
    p4_kernel<<<64, 256, 0, stream>>>(h);
}